// Round 1
// baseline (389.251 us; speedup 1.0000x reference)
//
#include <hip/hip_runtime.h>

#define Hh 160
#define Ww 160
#define HW 25600
#define Bb 8
#define Cc 64
#define Oo 64
#define NPIX (Bb * HW)   // 204800

typedef __bf16 bf16x8 __attribute__((ext_vector_type(8)));
typedef float  f32x4  __attribute__((ext_vector_type(4)));
typedef float  f32x2  __attribute__((ext_vector_type(2)));

__device__ inline unsigned rnd_bf(float a) {
    unsigned u = __float_as_uint(a);
    return (u + 0x7FFFu + ((u >> 16) & 1u)) >> 16;   // RNE f32->bf16 (prep only)
}
// fast round-half-up pack of two f32 -> packed bf16x2 (3 VALU ops)
__device__ inline unsigned pack_bf2(float a, float b) {
    unsigned ua = __float_as_uint(a) + 0x8000u;
    unsigned ub = __float_as_uint(b) + 0x8000u;
    return __builtin_amdgcn_perm(ub, ua, 0x07060302);
}
__device__ inline f32x2 up2(unsigned u) {
    f32x2 r;
    r.x = __uint_as_float(u << 16);
    r.y = __uint_as_float(u & 0xffff0000u);
    return r;
}
__device__ inline unsigned blend4(unsigned u00, unsigned u01, unsigned u10, unsigned u11,
                                  float w00, float w01, float w10, float w11) {
    f32x2 r = up2(u00) * w00 + up2(u01) * w01 + up2(u10) * w10 + up2(u11) * w11;
    return pack_bf2(r.x, r.y);
}
union UV { uint4 u; bf16x8 v; };
__device__ inline bf16x8 as_bf(uint4 u) { UV c; c.u = u; return c.v; }

// ---- prep: wtb[k][o 64][c] bf16 ; woffb[k][o pad32][c] bf16 ; BN fold ---------
__global__ __launch_bounds__(256) void prep_kernel(
    const float* __restrict__ w_dcn, const float* __restrict__ b_dcn,
    const float* __restrict__ w_off,
    const float* __restrict__ gamma, const float* __restrict__ beta,
    const float* __restrict__ run_mean, const float* __restrict__ run_var,
    unsigned short* __restrict__ wtb, unsigned short* __restrict__ woffb,
    float* __restrict__ scaleb)
{
    int i = blockIdx.x * 256 + threadIdx.x;
    if (i < 9 * Oo * Cc) {                 // wtb: [k][o][c]
        int k = i >> 12, rem = i & 4095;
        int o = rem >> 6, c = rem & 63;
        wtb[i] = (unsigned short)rnd_bf(w_dcn[(o * Cc + c) * 9 + k]);
    }
    if (i < 9 * 32 * Cc) {                 // woffb: [k][o pad32][c]
        int k = i >> 11, rem = i & 2047;
        int o = rem >> 6, c = rem & 63;
        float v = (o < 18) ? w_off[(o * Cc + c) * 9 + k] : 0.0f;
        woffb[i] = (unsigned short)rnd_bf(v);
    }
    if (i < Oo) {
        float inv = gamma[i] * rsqrtf(run_var[i] + 1e-5f);
        scaleb[i]      = inv;
        scaleb[Oo + i] = b_dcn[i] * inv + (beta[i] - run_mean[i] * inv);
    }
}

// ---- transpose x: NCHW fp32 -> NHWC bf16, LDS tile, coalesced both sides ------
// XCD swizzle matches dcn_kernel: image b is produced AND consumed on XCD b,
// so the 3.27 MB NHWC image stays resident in that XCD's 4 MB L2.
__global__ __launch_bounds__(256, 4) void xpose_kernel(
    const float* __restrict__ x, unsigned short* __restrict__ xhwc)
{
    __shared__ float tile[64 * 65];
    int blk = blockIdx.x;                  // 3200
    int nb  = (blk & 7) * 400 + (blk >> 3);
    int b = nb / 400, hw0 = (nb % 400) * 64;
    int t = threadIdx.x;
    int lane = t & 63, grp = t >> 6;

    const float* xp = x + (size_t)b * Cc * HW + hw0 + lane;
#pragma unroll
    for (int i = 0; i < 16; ++i) {
        int c = i * 4 + grp;
        tile[lane * 65 + c] = xp[(size_t)c * HW];
    }
    __syncthreads();

    int px  = t >> 2;                      // 0..63
    int ch0 = (t & 3) * 16;
    const float* row = tile + px * 65 + ch0;
    unsigned u[8];
#pragma unroll
    for (int j = 0; j < 8; ++j) u[j] = pack_bf2(row[2 * j], row[2 * j + 1]);
    unsigned short* dst = xhwc + ((size_t)(b * HW + hw0 + px)) * 64 + ch0;
    *(uint4*)dst       = make_uint4(u[0], u[1], u[2], u[3]);
    *(uint4*)(dst + 8) = make_uint4(u[4], u[5], u[6], u[7]);
}

// gather double-buffer: 8 raw uint4 (4 corners x lo/hi) + 4 bilinear weights.
// All indices are compile-time literals -> SROA keeps it in registers.
struct GBuf { uint4 g[8]; float w[4]; };

// ---- fused: offset-conv(MFMA) + deform-sample + projection(MFMA) + BN + ReLU --
// v2: ZERO barriers. Offsets are wave-private (each wave writes/reads only its
// own 16 pixels in offb), so no cross-wave data flow exists. MFMA B-operands
// load straight from the L1/L2-resident global tables (8 KB working set/tap)
// instead of LDS double-buffering. Gathers software-pipelined 1 tap deep with
// vmcnt-in-order-safe issue order: B(k) issued BEFORE G(k+1), so the MFMA's
// B-wait (vmcnt<=8) never drains the prefetched gathers.
__global__ __launch_bounds__(256, 3) void dcn_kernel(
    const unsigned short* __restrict__ xhwc,
    const unsigned short* __restrict__ wtb,     // [9][64][64]
    const unsigned short* __restrict__ woffb,   // [9][32][64]
    const float* __restrict__ b_off,
    const float* __restrict__ scaleb,
    float* __restrict__ out)
{
    __shared__ __align__(16) float offb[64 * 20];   // 5120 B, stride 20 (8B-aligned pairs)

    const int t = threadIdx.x;
    const int lane = t & 63, wv = t >> 6;
    const int m = lane & 15, quad = lane >> 4;

    int blk = blockIdx.x;
    int nb  = (blk & 7) * 400 + (blk >> 3);   // XCD slab swizzle: 1 image/XCD
    int b   = nb / 400;
    int hw0 = (nb % 400) * 64;
    int p   = wv * 16 + m;                 // this lane's pixel
    int hw  = hw0 + p;
    int h   = hw / Ww, w = hw % Ww;

    const size_t bbase = (size_t)b * HW;
    const unsigned short* xq = xhwc + bbase * 64 + quad * 8;

    // ================= phase 1: offset conv (B direct from global) =============
    f32x4 oa0 = {0,0,0,0}, oa1 = {0,0,0,0};
#pragma unroll
    for (int k = 0; k < 9; ++k) {
        int hp = h + (k / 3) - 1, wp = w + (k % 3) - 1;
        bool ok = (hp >= 0) & (hp < Hh) & (wp >= 0) & (wp < Ww);
        int hps = min(max(hp, 0), Hh - 1), wps = min(max(wp, 0), Ww - 1);
        const unsigned short* src = xq + (size_t)(hps * Ww + wps) * 64;
        uint4 r0 = *(const uint4*)(src);
        uint4 r1 = *(const uint4*)(src + 32);
        if (!ok) { r0 = make_uint4(0,0,0,0); r1 = make_uint4(0,0,0,0); }
        bf16x8 a0 = as_bf(r0), a1 = as_bf(r1);

        const unsigned short* wof = woffb + k * 2048 + quad * 8;
        bf16x8 b00 = *(const bf16x8*)(wof + m * 64);
        bf16x8 b01 = *(const bf16x8*)(wof + m * 64 + 32);
        bf16x8 b10 = *(const bf16x8*)(wof + (m + 16) * 64);
        bf16x8 b11 = *(const bf16x8*)(wof + (m + 16) * 64 + 32);
        oa0 = __builtin_amdgcn_mfma_f32_16x16x32_bf16(a0, b00, oa0, 0, 0, 0);
        oa0 = __builtin_amdgcn_mfma_f32_16x16x32_bf16(a1, b01, oa0, 0, 0, 0);
        oa1 = __builtin_amdgcn_mfma_f32_16x16x32_bf16(a0, b10, oa1, 0, 0, 0);
        oa1 = __builtin_amdgcn_mfma_f32_16x16x32_bf16(a1, b11, oa1, 0, 0, 0);
    }

    // offsets -> LDS (wave-private rows; same-wave ds_write->ds_read ordering
    // is handled by compiler lgkmcnt — no barrier needed)
    {
        float bo0 = b_off[m];
        float bo1 = (m < 2) ? b_off[16 + m] : 0.0f;
#pragma unroll
        for (int r = 0; r < 4; ++r) {
            int pp = wv * 16 + quad * 4 + r;
            offb[pp * 20 + m] = oa0[r] + bo0;
            if (m < 2) offb[pp * 20 + 16 + m] = oa1[r] + bo1;
        }
    }

    // ================= phase 2: deform sample + projection =================
    f32x4 c0 = {0,0,0,0}, c1 = {0,0,0,0}, c2 = {0,0,0,0}, c3 = {0,0,0,0};
    const int p20 = p * 20;
    bf16x8 Bq0, Bq1, Bq2, Bq3, Bq4, Bq5, Bq6, Bq7;

#define ISSUE(K, X) do {                                                       \
    f32x2 _o = *(const f32x2*)&offb[p20 + 2 * (K)];                            \
    float _py = (float)(h + (K) / 3 - 1) + _o.x;                               \
    float _px = (float)(w + (K) % 3 - 1) + _o.y;                               \
    float _y0f = floorf(_py), _x0f = floorf(_px);                              \
    float _fy = _py - _y0f, _fx = _px - _x0f;                                  \
    int _y0 = (int)_y0f, _x0 = (int)_x0f;                                      \
    int _y1 = _y0 + 1, _x1 = _x0 + 1;                                          \
    bool _vy0 = (_y0 >= 0) & (_y0 < Hh), _vy1 = (_y1 >= 0) & (_y1 < Hh);       \
    bool _vx0 = (_x0 >= 0) & (_x0 < Ww), _vx1 = (_x1 >= 0) & (_x1 < Ww);       \
    X.w[0] = (_vy0 & _vx0) ? (1.0f - _fy) * (1.0f - _fx) : 0.0f;               \
    X.w[1] = (_vy0 & _vx1) ? (1.0f - _fy) * _fx : 0.0f;                        \
    X.w[2] = (_vy1 & _vx0) ? _fy * (1.0f - _fx) : 0.0f;                        \
    X.w[3] = (_vy1 & _vx1) ? _fy * _fx : 0.0f;                                 \
    int _cy0 = min(max(_y0, 0), Hh - 1), _cy1 = min(max(_y1, 0), Hh - 1);      \
    int _cx0 = min(max(_x0, 0), Ww - 1), _cx1 = min(max(_x1, 0), Ww - 1);      \
    const unsigned short* _s00 = xq + (size_t)(_cy0 * Ww + _cx0) * 64;         \
    const unsigned short* _s01 = xq + (size_t)(_cy0 * Ww + _cx1) * 64;         \
    const unsigned short* _s10 = xq + (size_t)(_cy1 * Ww + _cx0) * 64;         \
    const unsigned short* _s11 = xq + (size_t)(_cy1 * Ww + _cx1) * 64;         \
    X.g[0] = *(const uint4*)(_s00); X.g[1] = *(const uint4*)(_s00 + 32);       \
    X.g[2] = *(const uint4*)(_s01); X.g[3] = *(const uint4*)(_s01 + 32);       \
    X.g[4] = *(const uint4*)(_s10); X.g[5] = *(const uint4*)(_s10 + 32);       \
    X.g[6] = *(const uint4*)(_s11); X.g[7] = *(const uint4*)(_s11 + 32);       \
} while (0)

#define LOADB(K) do {                                                          \
    const unsigned short* _wq = wtb + (K) * 4096 + quad * 8;                   \
    Bq0 = *(const bf16x8*)(_wq + m * 64);                                      \
    Bq1 = *(const bf16x8*)(_wq + m * 64 + 32);                                 \
    Bq2 = *(const bf16x8*)(_wq + (m + 16) * 64);                               \
    Bq3 = *(const bf16x8*)(_wq + (m + 16) * 64 + 32);                          \
    Bq4 = *(const bf16x8*)(_wq + (m + 32) * 64);                               \
    Bq5 = *(const bf16x8*)(_wq + (m + 32) * 64 + 32);                          \
    Bq6 = *(const bf16x8*)(_wq + (m + 48) * 64);                               \
    Bq7 = *(const bf16x8*)(_wq + (m + 48) * 64 + 32);                          \
} while (0)

#define MATH(X) do {                                                           \
    uint4 _o0, _o1;                                                            \
    _o0.x = blend4(X.g[0].x, X.g[2].x, X.g[4].x, X.g[6].x,                     \
                   X.w[0], X.w[1], X.w[2], X.w[3]);                            \
    _o0.y = blend4(X.g[0].y, X.g[2].y, X.g[4].y, X.g[6].y,                     \
                   X.w[0], X.w[1], X.w[2], X.w[3]);                            \
    _o0.z = blend4(X.g[0].z, X.g[2].z, X.g[4].z, X.g[6].z,                     \
                   X.w[0], X.w[1], X.w[2], X.w[3]);                            \
    _o0.w = blend4(X.g[0].w, X.g[2].w, X.g[4].w, X.g[6].w,                     \
                   X.w[0], X.w[1], X.w[2], X.w[3]);                            \
    _o1.x = blend4(X.g[1].x, X.g[3].x, X.g[5].x, X.g[7].x,                     \
                   X.w[0], X.w[1], X.w[2], X.w[3]);                            \
    _o1.y = blend4(X.g[1].y, X.g[3].y, X.g[5].y, X.g[7].y,                     \
                   X.w[0], X.w[1], X.w[2], X.w[3]);                            \
    _o1.z = blend4(X.g[1].z, X.g[3].z, X.g[5].z, X.g[7].z,                     \
                   X.w[0], X.w[1], X.w[2], X.w[3]);                            \
    _o1.w = blend4(X.g[1].w, X.g[3].w, X.g[5].w, X.g[7].w,                     \
                   X.w[0], X.w[1], X.w[2], X.w[3]);                            \
    bf16x8 _A0 = as_bf(_o0), _A1 = as_bf(_o1);                                 \
    c0 = __builtin_amdgcn_mfma_f32_16x16x32_bf16(_A0, Bq0, c0, 0, 0, 0);       \
    c0 = __builtin_amdgcn_mfma_f32_16x16x32_bf16(_A1, Bq1, c0, 0, 0, 0);       \
    c1 = __builtin_amdgcn_mfma_f32_16x16x32_bf16(_A0, Bq2, c1, 0, 0, 0);       \
    c1 = __builtin_amdgcn_mfma_f32_16x16x32_bf16(_A1, Bq3, c1, 0, 0, 0);       \
    c2 = __builtin_amdgcn_mfma_f32_16x16x32_bf16(_A0, Bq4, c2, 0, 0, 0);       \
    c2 = __builtin_amdgcn_mfma_f32_16x16x32_bf16(_A1, Bq5, c2, 0, 0, 0);       \
    c3 = __builtin_amdgcn_mfma_f32_16x16x32_bf16(_A0, Bq6, c3, 0, 0, 0);       \
    c3 = __builtin_amdgcn_mfma_f32_16x16x32_bf16(_A1, Bq7, c3, 0, 0, 0);       \
} while (0)

    GBuf Ga, Gb;
    // prologue: tap 0 gathers + tap 0 weights in flight
    ISSUE(0, Ga); LOADB(0);
    // steady state: ISSUE(k+1) -> MATH(k) -> LOADB(k+1)
    ISSUE(1, Gb); MATH(Ga); LOADB(1);
    ISSUE(2, Ga); MATH(Gb); LOADB(2);
    ISSUE(3, Gb); MATH(Ga); LOADB(3);
    ISSUE(4, Ga); MATH(Gb); LOADB(4);
    ISSUE(5, Gb); MATH(Ga); LOADB(5);
    ISSUE(6, Ga); MATH(Gb); LOADB(6);
    ISSUE(7, Gb); MATH(Ga); LOADB(7);
    ISSUE(8, Ga); MATH(Gb); LOADB(8);
    MATH(Ga);

#undef ISSUE
#undef LOADB
#undef MATH

    // ---- epilogue: direct float4 stores (16 lines/instr, 64 B aligned) ----
#pragma unroll
    for (int nt = 0; nt < 4; ++nt) {
        f32x4 a = (nt == 0) ? c0 : (nt == 1) ? c1 : (nt == 2) ? c2 : c3;
        int o = nt * 16 + m;
        float sc = scaleb[o];
        float bs = scaleb[Oo + o];
        float4 r;
        r.x = fmaxf(a[0] * sc + bs, 0.0f);
        r.y = fmaxf(a[1] * sc + bs, 0.0f);
        r.z = fmaxf(a[2] * sc + bs, 0.0f);
        r.w = fmaxf(a[3] * sc + bs, 0.0f);
        float* op = out + ((size_t)b * Oo + o) * HW + hw0 + wv * 16 + quad * 4;
        *(float4*)op = r;
    }
}

extern "C" void kernel_launch(void* const* d_in, const int* in_sizes, int n_in,
                              void* d_out, int out_size, void* d_ws, size_t ws_size,
                              hipStream_t stream) {
    const float* x        = (const float*)d_in[0];
    const float* w_off    = (const float*)d_in[1];
    const float* b_off    = (const float*)d_in[2];
    const float* w_dcn    = (const float*)d_in[3];
    const float* b_dcn    = (const float*)d_in[4];
    const float* gamma    = (const float*)d_in[5];
    const float* beta     = (const float*)d_in[6];
    const float* run_mean = (const float*)d_in[7];
    const float* run_var  = (const float*)d_in[8];
    float* out = (float*)d_out;

    // workspace: xhwc (26.2 MB) | wtb | woffb | scaleb
    unsigned short* xhwc  = (unsigned short*)d_ws;
    unsigned short* wtb   = xhwc + (size_t)NPIX * 64;          // 9*64*64 bf16
    unsigned short* woffb = wtb + 9 * Oo * Cc;                 // 9*32*64 bf16
    float* scaleb         = (float*)(woffb + 9 * 32 * Cc);     // 128 floats

    prep_kernel<<<(9 * Oo * Cc + 255) / 256, 256, 0, stream>>>(
        w_dcn, b_dcn, w_off, gamma, beta, run_mean, run_var, wtb, woffb, scaleb);

    xpose_kernel<<<NPIX / 64, 256, 0, stream>>>(x, xhwc);

    dcn_kernel<<<NPIX / 64, 256, 0, stream>>>(xhwc, wtb, woffb, b_off, scaleb, out);
}

// Round 2
// 249.462 us; speedup vs baseline: 1.5604x; 1.5604x over previous
//
#include <hip/hip_runtime.h>

#define Hh 160
#define Ww 160
#define HW 25600
#define Bb 8
#define Cc 64
#define Oo 64
#define NPIX (Bb * HW)   // 204800
#define WROW 72          // shorts per padded LDS weight row (144 B, 16B-aligned)

typedef __bf16 bf16x8 __attribute__((ext_vector_type(8)));
typedef float  f32x4  __attribute__((ext_vector_type(4)));
typedef float  f32x2  __attribute__((ext_vector_type(2)));

__device__ inline unsigned rnd_bf(float a) {
    unsigned u = __float_as_uint(a);
    return (u + 0x7FFFu + ((u >> 16) & 1u)) >> 16;   // RNE f32->bf16 (prep only)
}
__device__ inline unsigned pack_bf2(float a, float b) {
    unsigned ua = __float_as_uint(a) + 0x8000u;
    unsigned ub = __float_as_uint(b) + 0x8000u;
    return __builtin_amdgcn_perm(ub, ua, 0x07060302);
}
__device__ inline f32x2 up2(unsigned u) {
    f32x2 r;
    r.x = __uint_as_float(u << 16);
    r.y = __uint_as_float(u & 0xffff0000u);
    return r;
}
__device__ inline unsigned blend4(unsigned u00, unsigned u01, unsigned u10, unsigned u11,
                                  float w00, float w01, float w10, float w11) {
    f32x2 r = up2(u00) * w00 + up2(u01) * w01 + up2(u10) * w10 + up2(u11) * w11;
    return pack_bf2(r.x, r.y);
}
union UV { uint4 u; bf16x8 v; };
__device__ inline bf16x8 as_bf(uint4 u) { UV c; c.u = u; return c.v; }

// ---- prep: wtb[k][o 64][c] bf16 ; woffb[k][o pad32][c] bf16 ; BN fold ---------
__global__ __launch_bounds__(256) void prep_kernel(
    const float* __restrict__ w_dcn, const float* __restrict__ b_dcn,
    const float* __restrict__ w_off,
    const float* __restrict__ gamma, const float* __restrict__ beta,
    const float* __restrict__ run_mean, const float* __restrict__ run_var,
    unsigned short* __restrict__ wtb, unsigned short* __restrict__ woffb,
    float* __restrict__ scaleb)
{
    int i = blockIdx.x * 256 + threadIdx.x;
    if (i < 9 * Oo * Cc) {                 // wtb: [k][o][c]
        int k = i >> 12, rem = i & 4095;
        int o = rem >> 6, c = rem & 63;
        wtb[i] = (unsigned short)rnd_bf(w_dcn[(o * Cc + c) * 9 + k]);
    }
    if (i < 9 * 32 * Cc) {                 // woffb: [k][o pad32][c]
        int k = i >> 11, rem = i & 2047;
        int o = rem >> 6, c = rem & 63;
        float v = (o < 18) ? w_off[(o * Cc + c) * 9 + k] : 0.0f;
        woffb[i] = (unsigned short)rnd_bf(v);
    }
    if (i < Oo) {
        float inv = gamma[i] * rsqrtf(run_var[i] + 1e-5f);
        scaleb[i]      = inv;
        scaleb[Oo + i] = b_dcn[i] * inv + (beta[i] - run_mean[i] * inv);
    }
}

// ---- transpose x: NCHW fp32 -> NHWC bf16; XCD swizzle matches dcn_kernel ------
__global__ __launch_bounds__(256, 4) void xpose_kernel(
    const float* __restrict__ x, unsigned short* __restrict__ xhwc)
{
    __shared__ float tile[64 * 65];
    int blk = blockIdx.x;                  // 3200
    int nb  = (blk & 7) * 400 + (blk >> 3);
    int b = nb / 400, hw0 = (nb % 400) * 64;
    int t = threadIdx.x;
    int lane = t & 63, grp = t >> 6;

    const float* xp = x + (size_t)b * Cc * HW + hw0 + lane;
#pragma unroll
    for (int i = 0; i < 16; ++i) {
        int c = i * 4 + grp;
        tile[lane * 65 + c] = xp[(size_t)c * HW];
    }
    __syncthreads();

    int px  = t >> 2;                      // 0..63
    int ch0 = (t & 3) * 16;
    const float* row = tile + px * 65 + ch0;
    unsigned u[8];
#pragma unroll
    for (int j = 0; j < 8; ++j) u[j] = pack_bf2(row[2 * j], row[2 * j + 1]);
    unsigned short* dst = xhwc + ((size_t)(b * HW + hw0 + px)) * 64 + ch0;
    *(uint4*)dst       = make_uint4(u[0], u[1], u[2], u[3]);
    *(uint4*)(dst + 8) = make_uint4(u[4], u[5], u[6], u[7]);
}

// gather buffer: 8 raw uint4 (4 corners x lo/hi) + 4 bilinear weights.
struct GBuf { uint4 g[8]; float w[4]; };

// scheduling pins: nothing (incl. memory ops) moves across these.
#define PIN() do { __builtin_amdgcn_sched_barrier(0); \
                   asm volatile("" ::: "memory"); } while (0)
// raw barrier: drain LDS ops only — prefetched VMEM loads stay in flight
// (this is the whole point: __syncthreads would force vmcnt(0)).
#define LBAR() do { PIN(); \
                    asm volatile("s_waitcnt lgkmcnt(0)" ::: "memory"); \
                    __builtin_amdgcn_s_barrier(); \
                    PIN(); } while (0)

// ---- fused: offset-conv(MFMA) + deform-sample + projection(MFMA) + BN + ReLU --
// v3: v1's LDS-dbuf structure, but every global load (A rows, gathers, weight
// staging) is issued ONE TAP EARLY and survives the barrier (lgkm-only drain).
// Staging ds_write is moved AFTER the MFMA block (T14 write-late). sched
// pins stop the compiler from re-sinking the prefetches (v2's failure).
__global__ __launch_bounds__(256, 2) void dcn_kernel(
    const unsigned short* __restrict__ xhwc,
    const unsigned short* __restrict__ wtb,     // [9][64][64]
    const unsigned short* __restrict__ woffb,   // [9][32][64]
    const float* __restrict__ b_off,
    const float* __restrict__ scaleb,
    float* __restrict__ out)
{
    __shared__ __align__(16) short wdcn[2 * 64 * WROW];   // 18432 B
    __shared__ __align__(16) short woff[2 * 32 * WROW];   //  9216 B
    __shared__ __align__(16) float offb[64 * 20];         //  5120 B  (tot 32768)

    const int t = threadIdx.x;
    const int lane = t & 63, wv = t >> 6;
    const int m = lane & 15, quad = lane >> 4;

    int blk = blockIdx.x;
    int nb  = (blk & 7) * 400 + (blk >> 3);   // XCD slab swizzle: 1 image/XCD
    int b   = nb / 400;
    int hw0 = (nb % 400) * 64;
    int p   = wv * 16 + m;                 // this lane's pixel
    int hw  = hw0 + p;
    int h   = hw / Ww, w = hw % Ww;

    const size_t bbase = (size_t)b * HW;
    const unsigned short* xq = xhwc + bbase * 64 + quad * 8;
    const uint4* wtb4  = (const uint4*)wtb;
    const uint4* wofb4 = (const uint4*)woffb;

    // ================= phase 1: offset conv =================
    f32x4 oa0 = {0,0,0,0}, oa1 = {0,0,0,0};
    uint4 wsv;                      // staged woff chunk (1/thread)
    uint4 pr0a, pr1a, pr0b, pr1b;   // A-row prefetch double buffer

#define A_ISSUE(K, R0, R1) do {                                                \
    int _hp = h + (K) / 3 - 1, _wp = w + (K) % 3 - 1;                          \
    int _hps = min(max(_hp, 0), Hh - 1), _wps = min(max(_wp, 0), Ww - 1);      \
    const unsigned short* _src = xq + (size_t)(_hps * Ww + _wps) * 64;         \
    R0 = *(const uint4*)(_src);                                                \
    R1 = *(const uint4*)(_src + 32);                                           \
} while (0)

#define TAP1(K, R0c, R1c, R0n, R1n) do {                                       \
    if ((K) < 8) {                                                             \
        wsv = wofb4[((K) + 1) * 256 + t];      /* stage-load W(k+1) */         \
        A_ISSUE((K) + 1, R0n, R1n);            /* prefetch A(k+1)   */         \
        PIN();                                                                 \
    }                                                                          \
    {                                                                          \
        int _hp = h + (K) / 3 - 1, _wp = w + (K) % 3 - 1;                      \
        bool _ok = (_hp >= 0) & (_hp < Hh) & (_wp >= 0) & (_wp < Ww);          \
        uint4 _r0 = R0c, _r1 = R1c;                                            \
        if (!_ok) { _r0 = make_uint4(0,0,0,0); _r1 = make_uint4(0,0,0,0); }    \
        bf16x8 _a0 = as_bf(_r0), _a1 = as_bf(_r1);                             \
        const short* _wb = woff + ((K) & 1) * 32 * WROW + quad * 8;            \
        bf16x8 _b00 = *(const bf16x8*)(_wb + m * WROW);                        \
        bf16x8 _b01 = *(const bf16x8*)(_wb + m * WROW + 32);                   \
        bf16x8 _b10 = *(const bf16x8*)(_wb + (m + 16) * WROW);                 \
        bf16x8 _b11 = *(const bf16x8*)(_wb + (m + 16) * WROW + 32);            \
        oa0 = __builtin_amdgcn_mfma_f32_16x16x32_bf16(_a0, _b00, oa0, 0,0,0);  \
        oa0 = __builtin_amdgcn_mfma_f32_16x16x32_bf16(_a1, _b01, oa0, 0,0,0);  \
        oa1 = __builtin_amdgcn_mfma_f32_16x16x32_bf16(_a0, _b10, oa1, 0,0,0);  \
        oa1 = __builtin_amdgcn_mfma_f32_16x16x32_bf16(_a1, _b11, oa1, 0,0,0);  \
    }                                                                          \
    if ((K) < 8) {                                                             \
        PIN();                                 /* write-late staging */        \
        *(uint4*)((char*)(woff + (((K) + 1) & 1) * 32 * WROW)                  \
                  + (t >> 3) * (WROW * 2) + (t & 7) * 16) = wsv;               \
        LBAR();                                                                \
    }                                                                          \
} while (0)

    // prologue: stage tap0 weights, prefetch A(0)
    wsv = wofb4[t];
    A_ISSUE(0, pr0a, pr1a);
    *(uint4*)((char*)woff + (t >> 3) * (WROW * 2) + (t & 7) * 16) = wsv;
    LBAR();

    TAP1(0, pr0a, pr1a, pr0b, pr1b);
    TAP1(1, pr0b, pr1b, pr0a, pr1a);
    TAP1(2, pr0a, pr1a, pr0b, pr1b);
    TAP1(3, pr0b, pr1b, pr0a, pr1a);
    TAP1(4, pr0a, pr1a, pr0b, pr1b);
    TAP1(5, pr0b, pr1b, pr0a, pr1a);
    TAP1(6, pr0a, pr1a, pr0b, pr1b);
    TAP1(7, pr0b, pr1b, pr0a, pr1a);
    TAP1(8, pr0a, pr1a, pr0b, pr1b);
#undef TAP1
#undef A_ISSUE

    // offsets -> LDS (wave-private rows: writer wave == reader wave, no barrier)
    {
        float bo0 = b_off[m];
        float bo1 = (m < 2) ? b_off[16 + m] : 0.0f;
#pragma unroll
        for (int r = 0; r < 4; ++r) {
            int pp = wv * 16 + quad * 4 + r;
            offb[pp * 20 + m] = oa0[r] + bo0;
            if (m < 2) offb[pp * 20 + 16 + m] = oa1[r] + bo1;
        }
    }

    // ================= phase 2: deform sample + projection =================
    f32x4 c0 = {0,0,0,0}, c1 = {0,0,0,0}, c2 = {0,0,0,0}, c3 = {0,0,0,0};
    const int p20 = p * 20;
    uint4 sv0, sv1;                 // staged wdcn chunks (2/thread)
    GBuf Ga, Gb;

#define ISSUE(K, X) do {                                                       \
    f32x2 _o = *(const f32x2*)&offb[p20 + 2 * (K)];                            \
    float _py = (float)(h + (K) / 3 - 1) + _o.x;                               \
    float _px = (float)(w + (K) % 3 - 1) + _o.y;                               \
    float _y0f = floorf(_py), _x0f = floorf(_px);                              \
    float _fy = _py - _y0f, _fx = _px - _x0f;                                  \
    int _y0 = (int)_y0f, _x0 = (int)_x0f;                                      \
    int _y1 = _y0 + 1, _x1 = _x0 + 1;                                          \
    bool _vy0 = (_y0 >= 0) & (_y0 < Hh), _vy1 = (_y1 >= 0) & (_y1 < Hh);       \
    bool _vx0 = (_x0 >= 0) & (_x0 < Ww), _vx1 = (_x1 >= 0) & (_x1 < Ww);       \
    X.w[0] = (_vy0 & _vx0) ? (1.0f - _fy) * (1.0f - _fx) : 0.0f;               \
    X.w[1] = (_vy0 & _vx1) ? (1.0f - _fy) * _fx : 0.0f;                        \
    X.w[2] = (_vy1 & _vx0) ? _fy * (1.0f - _fx) : 0.0f;                        \
    X.w[3] = (_vy1 & _vx1) ? _fy * _fx : 0.0f;                                 \
    int _cy0 = min(max(_y0, 0), Hh - 1), _cy1 = min(max(_y1, 0), Hh - 1);      \
    int _cx0 = min(max(_x0, 0), Ww - 1), _cx1 = min(max(_x1, 0), Ww - 1);      \
    const unsigned short* _s00 = xq + (size_t)(_cy0 * Ww + _cx0) * 64;         \
    const unsigned short* _s01 = xq + (size_t)(_cy0 * Ww + _cx1) * 64;         \
    const unsigned short* _s10 = xq + (size_t)(_cy1 * Ww + _cx0) * 64;         \
    const unsigned short* _s11 = xq + (size_t)(_cy1 * Ww + _cx1) * 64;         \
    X.g[0] = *(const uint4*)(_s00); X.g[1] = *(const uint4*)(_s00 + 32);       \
    X.g[2] = *(const uint4*)(_s01); X.g[3] = *(const uint4*)(_s01 + 32);       \
    X.g[4] = *(const uint4*)(_s10); X.g[5] = *(const uint4*)(_s10 + 32);       \
    X.g[6] = *(const uint4*)(_s11); X.g[7] = *(const uint4*)(_s11 + 32);       \
} while (0)

#define MATH(X, K) do {                                                        \
    uint4 _o0, _o1;                                                            \
    _o0.x = blend4(X.g[0].x, X.g[2].x, X.g[4].x, X.g[6].x,                     \
                   X.w[0], X.w[1], X.w[2], X.w[3]);                            \
    _o0.y = blend4(X.g[0].y, X.g[2].y, X.g[4].y, X.g[6].y,                     \
                   X.w[0], X.w[1], X.w[2], X.w[3]);                            \
    _o0.z = blend4(X.g[0].z, X.g[2].z, X.g[4].z, X.g[6].z,                     \
                   X.w[0], X.w[1], X.w[2], X.w[3]);                            \
    _o0.w = blend4(X.g[0].w, X.g[2].w, X.g[4].w, X.g[6].w,                     \
                   X.w[0], X.w[1], X.w[2], X.w[3]);                            \
    _o1.x = blend4(X.g[1].x, X.g[3].x, X.g[5].x, X.g[7].x,                     \
                   X.w[0], X.w[1], X.w[2], X.w[3]);                            \
    _o1.y = blend4(X.g[1].y, X.g[3].y, X.g[5].y, X.g[7].y,                     \
                   X.w[0], X.w[1], X.w[2], X.w[3]);                            \
    _o1.z = blend4(X.g[1].z, X.g[3].z, X.g[5].z, X.g[7].z,                     \
                   X.w[0], X.w[1], X.w[2], X.w[3]);                            \
    _o1.w = blend4(X.g[1].w, X.g[3].w, X.g[5].w, X.g[7].w,                     \
                   X.w[0], X.w[1], X.w[2], X.w[3]);                            \
    bf16x8 _A0 = as_bf(_o0), _A1 = as_bf(_o1);                                 \
    const short* _wq = wdcn + ((K) & 1) * 64 * WROW + quad * 8;                \
    bf16x8 _B0, _B1;                                                           \
    _B0 = *(const bf16x8*)(_wq + m * WROW);                                    \
    _B1 = *(const bf16x8*)(_wq + m * WROW + 32);                               \
    c0 = __builtin_amdgcn_mfma_f32_16x16x32_bf16(_A0, _B0, c0, 0, 0, 0);       \
    c0 = __builtin_amdgcn_mfma_f32_16x16x32_bf16(_A1, _B1, c0, 0, 0, 0);       \
    _B0 = *(const bf16x8*)(_wq + (m + 16) * WROW);                             \
    _B1 = *(const bf16x8*)(_wq + (m + 16) * WROW + 32);                        \
    c1 = __builtin_amdgcn_mfma_f32_16x16x32_bf16(_A0, _B0, c1, 0, 0, 0);       \
    c1 = __builtin_amdgcn_mfma_f32_16x16x32_bf16(_A1, _B1, c1, 0, 0, 0);       \
    _B0 = *(const bf16x8*)(_wq + (m + 32) * WROW);                             \
    _B1 = *(const bf16x8*)(_wq + (m + 32) * WROW + 32);                        \
    c2 = __builtin_amdgcn_mfma_f32_16x16x32_bf16(_A0, _B0, c2, 0, 0, 0);       \
    c2 = __builtin_amdgcn_mfma_f32_16x16x32_bf16(_A1, _B1, c2, 0, 0, 0);       \
    _B0 = *(const bf16x8*)(_wq + (m + 48) * WROW);                             \
    _B1 = *(const bf16x8*)(_wq + (m + 48) * WROW + 32);                        \
    c3 = __builtin_amdgcn_mfma_f32_16x16x32_bf16(_A0, _B0, c3, 0, 0, 0);       \
    c3 = __builtin_amdgcn_mfma_f32_16x16x32_bf16(_A1, _B1, c3, 0, 0, 0);       \
} while (0)

#define TAP2(K, Xc, Xn) do {                                                   \
    if ((K) < 8) {                                                             \
        const uint4* _g = wtb4 + ((K) + 1) * 512;                              \
        sv0 = _g[t]; sv1 = _g[t + 256];        /* stage-load B(k+1)  */        \
        ISSUE((K) + 1, Xn);                    /* prefetch gathers   */        \
        PIN();                                                                 \
    }                                                                          \
    MATH(Xc, K);                                                               \
    if ((K) < 8) {                                                             \
        PIN();                                 /* write-late staging */        \
        char* _wb = (char*)(wdcn + (((K) + 1) & 1) * 64 * WROW);               \
        *(uint4*)(_wb + (t >> 3) * (WROW * 2) + (t & 7) * 16) = sv0;           \
        *(uint4*)(_wb + ((t + 256) >> 3) * (WROW * 2)                          \
                      + ((t + 256) & 7) * 16) = sv1;                           \
        LBAR();                                                                \
    }                                                                          \
} while (0)

    // prologue: stage tap0 weights, prefetch gathers G(0)
    sv0 = wtb4[t]; sv1 = wtb4[t + 256];
    ISSUE(0, Ga);
    {
        char* _wb = (char*)wdcn;
        *(uint4*)(_wb + (t >> 3) * (WROW * 2) + (t & 7) * 16) = sv0;
        *(uint4*)(_wb + ((t + 256) >> 3) * (WROW * 2) + ((t + 256) & 7) * 16) = sv1;
    }
    LBAR();

    TAP2(0, Ga, Gb);
    TAP2(1, Gb, Ga);
    TAP2(2, Ga, Gb);
    TAP2(3, Gb, Ga);
    TAP2(4, Ga, Gb);
    TAP2(5, Gb, Ga);
    TAP2(6, Ga, Gb);
    TAP2(7, Gb, Ga);
    TAP2(8, Ga, Gb);

#undef TAP2
#undef MATH
#undef ISSUE

    // ---- epilogue: direct float4 stores (16 lines/instr, 64 B aligned) ----
#pragma unroll
    for (int nt = 0; nt < 4; ++nt) {
        f32x4 a = (nt == 0) ? c0 : (nt == 1) ? c1 : (nt == 2) ? c2 : c3;
        int o = nt * 16 + m;
        float sc = scaleb[o];
        float bs = scaleb[Oo + o];
        float4 r;
        r.x = fmaxf(a[0] * sc + bs, 0.0f);
        r.y = fmaxf(a[1] * sc + bs, 0.0f);
        r.z = fmaxf(a[2] * sc + bs, 0.0f);
        r.w = fmaxf(a[3] * sc + bs, 0.0f);
        float* op = out + ((size_t)b * Oo + o) * HW + hw0 + wv * 16 + quad * 4;
        *(float4*)op = r;
    }
}

extern "C" void kernel_launch(void* const* d_in, const int* in_sizes, int n_in,
                              void* d_out, int out_size, void* d_ws, size_t ws_size,
                              hipStream_t stream) {
    const float* x        = (const float*)d_in[0];
    const float* w_off    = (const float*)d_in[1];
    const float* b_off    = (const float*)d_in[2];
    const float* w_dcn    = (const float*)d_in[3];
    const float* b_dcn    = (const float*)d_in[4];
    const float* gamma    = (const float*)d_in[5];
    const float* beta     = (const float*)d_in[6];
    const float* run_mean = (const float*)d_in[7];
    const float* run_var  = (const float*)d_in[8];
    float* out = (float*)d_out;

    // workspace: xhwc (26.2 MB) | wtb | woffb | scaleb
    unsigned short* xhwc  = (unsigned short*)d_ws;
    unsigned short* wtb   = xhwc + (size_t)NPIX * 64;          // 9*64*64 bf16
    unsigned short* woffb = wtb + 9 * Oo * Cc;                 // 9*32*64 bf16
    float* scaleb         = (float*)(woffb + 9 * 32 * Cc);     // 128 floats

    prep_kernel<<<(9 * Oo * Cc + 255) / 256, 256, 0, stream>>>(
        w_dcn, b_dcn, w_off, gamma, beta, run_mean, run_var, wtb, woffb, scaleb);

    xpose_kernel<<<NPIX / 64, 256, 0, stream>>>(x, xhwc);

    dcn_kernel<<<NPIX / 64, 256, 0, stream>>>(xhwc, wtb, woffb, b_off, scaleb, out);
}